// Round 1
// baseline (2584.694 us; speedup 1.0000x reference)
//
#include <hip/hip_runtime.h>
#include <hip/hip_bf16.h>
#include <stdint.h>

// LSTM T=256, B=64, I=H=O=1024.
// Plan: (1) XG = X@Wx4 + b4 as one big bf16 GEMM, (2) 256 sequential step
// kernels computing H@Wh4 + cell update, (3) Y = Hall@Whq + bq as one GEMM.
// Workspace requirement: ~211 MB.

typedef __bf16 bf16x8 __attribute__((ext_vector_type(8)));
typedef float  f32x4  __attribute__((ext_vector_type(4)));

#define AS1 __attribute__((address_space(1)))
#define AS3 __attribute__((address_space(3)))

static __device__ __forceinline__ void gload_lds16(const void* g, void* l) {
  __builtin_amdgcn_global_load_lds((const AS1 void*)g, (AS3 void*)l, 16, 0, 0);
}

static __device__ __forceinline__ float sigm(float x) { return 1.f / (1.f + __expf(-x)); }
static __device__ __forceinline__ float tanh_fast(float x) { return 1.f - 2.f / (1.f + __expf(2.f * x)); }

// ---------------- prep kernels ----------------

__global__ void convert_x_kernel(const float* __restrict__ X, __hip_bfloat16* __restrict__ Xbf) {
  size_t i8 = (size_t)(blockIdx.x * 256 + threadIdx.x) * 8;
  float4 a = *(const float4*)(X + i8);
  float4 b = *(const float4*)(X + i8 + 4);
  union { __hip_bfloat16 h[8]; int4 v; } u;
  u.h[0] = __float2bfloat16(a.x); u.h[1] = __float2bfloat16(a.y);
  u.h[2] = __float2bfloat16(a.z); u.h[3] = __float2bfloat16(a.w);
  u.h[4] = __float2bfloat16(b.x); u.h[5] = __float2bfloat16(b.y);
  u.h[6] = __float2bfloat16(b.z); u.h[7] = __float2bfloat16(b.w);
  *(int4*)(Xbf + i8) = u.v;
}

__global__ void init_kernel(const float* __restrict__ H0, const float* __restrict__ C0,
                            const float* __restrict__ bi, const float* __restrict__ bf_,
                            const float* __restrict__ bo, const float* __restrict__ bc,
                            __hip_bfloat16* __restrict__ Hb0, float* __restrict__ Cws,
                            float* __restrict__ b4) {
  int e = blockIdx.x * 256 + threadIdx.x;
  if (e < 65536) {
    Hb0[e] = __float2bfloat16(H0[e]);
    Cws[e] = C0[e];
  } else {
    int i = e - 65536;
    if (i < 4096) {
      const float* p = (i < 1024) ? bi : (i < 2048) ? bf_ : (i < 3072) ? bo : bc;
      b4[i] = p[i & 1023];
    }
  }
}

struct PackArgs { const float* s[9]; };

// Transposed bf16 pack: dst[n][k] = src[k][n]  (B^T layout for MFMA B-frags)
__global__ void pack_weights_kernel(PackArgs pa, __hip_bfloat16* __restrict__ wxT,
                                    __hip_bfloat16* __restrict__ whT,
                                    __hip_bfloat16* __restrict__ whqT) {
  __shared__ float tile[32][33];
  int mz = blockIdx.z;
  const float* src = pa.s[mz];
  __hip_bfloat16* dst = (mz < 4) ? (wxT + (size_t)mz * 1048576)
                      : (mz < 8) ? (whT + (size_t)(mz - 4) * 1048576)
                                 : whqT;
  int c0 = blockIdx.x * 32, r0 = blockIdx.y * 32;
  int tx = threadIdx.x, ty = threadIdx.y;
#pragma unroll
  for (int i = 0; i < 4; ++i)
    tile[ty + 8 * i][tx] = src[(size_t)(r0 + ty + 8 * i) * 1024 + c0 + tx];
  __syncthreads();
#pragma unroll
  for (int i = 0; i < 4; ++i)
    dst[(size_t)(c0 + ty + 8 * i) * 1024 + r0 + tx] = __float2bfloat16(tile[tx][ty + 8 * i]);
}

// ---------------- big GEMM (phases 1 and 3) ----------------
// C[M][N] = A[M][1024] * B^T[N][1024] + bias ; 128x128 tile, 4 waves, BK=64.
// LDS tiles XOR-swizzled via pre-swizzled global_load_lds source.

template <bool OUT_BF16>
__global__ __launch_bounds__(256) void gemm_bt_kernel(
    const __hip_bfloat16* __restrict__ A,
    const __hip_bfloat16* __restrict__ B,
    const float* __restrict__ bias,
    void* __restrict__ Out, int N) {
  __shared__ char lds[32768];
  char* Alds = lds;
  char* Blds = lds + 16384;
  const int tid = threadIdx.x;
  const int lane = tid & 63, wave = tid >> 6;
  const int wm = wave >> 1, wn = wave & 1;
  const size_t m0 = (size_t)blockIdx.x * 128;
  const size_t n0 = (size_t)blockIdx.y * 128;

  const char* Ag = (const char*)A + m0 * 2048;
  const char* Bg = (const char*)B + n0 * 2048;

  int u_so[4];
#pragma unroll
  for (int c = 0; c < 4; ++c) {
    int u = c * 256 + tid;
    int row = u >> 3, cu = u & 7;
    u_so[c] = row * 2048 + ((cu * 16) ^ ((row & 7) << 4));
  }

  f32x4 acc[4][4] = {};
  const int lr = lane & 15;
  const int lk = (lane >> 4) << 4;   // 16B k-chunk per lane group
  const int ls = (lane & 7) << 4;    // XOR swizzle key (= row&7 since row%16==lr)

  for (int kt = 0; kt < 16; ++kt) {
    const char* Ak = Ag + kt * 128;
    const char* Bk = Bg + kt * 128;
#pragma unroll
    for (int c = 0; c < 4; ++c) {
      gload_lds16(Ak + u_so[c], Alds + c * 4096 + wave * 1024);
      gload_lds16(Bk + u_so[c], Blds + c * 4096 + wave * 1024);
    }
    __syncthreads();
#pragma unroll
    for (int kk = 0; kk < 2; ++kk) {
      bf16x8 af[4], bfr[4];
#pragma unroll
      for (int m = 0; m < 4; ++m) {
        int row = wm * 64 + m * 16 + lr;
        af[m] = *(const bf16x8*)(Alds + row * 128 + ((kk * 64 + lk) ^ ls));
      }
#pragma unroll
      for (int n = 0; n < 4; ++n) {
        int row = wn * 64 + n * 16 + lr;
        bfr[n] = *(const bf16x8*)(Blds + row * 128 + ((kk * 64 + lk) ^ ls));
      }
#pragma unroll
      for (int m = 0; m < 4; ++m)
#pragma unroll
        for (int n = 0; n < 4; ++n)
          acc[m][n] = __builtin_amdgcn_mfma_f32_16x16x32_bf16(af[m], bfr[n], acc[m][n], 0, 0, 0);
    }
    __syncthreads();
  }

  const size_t crow0 = m0 + wm * 64;
  const size_t ccol0 = n0 + wn * 64;
#pragma unroll
  for (int n = 0; n < 4; ++n) {
    size_t col = ccol0 + n * 16 + lr;
    float bv = bias[col];
#pragma unroll
    for (int m = 0; m < 4; ++m) {
      size_t row0 = crow0 + m * 16 + ((lane >> 4) << 2);
#pragma unroll
      for (int r = 0; r < 4; ++r) {
        float v = acc[m][n][r] + bv;
        size_t o = (row0 + r) * (size_t)N + col;
        if (OUT_BF16) ((__hip_bfloat16*)Out)[o] = __float2bfloat16(v);
        else          ((float*)Out)[o] = v;
      }
    }
  }
}

// ---------------- sequential LSTM step ----------------
// grid=128 (jb: 8 hidden cols each -> 32 gate-cols), block=256 (4 waves).
// Wave m handles batch rows [16m,16m+16): A-frags straight from global Hprev,
// B-frags from 64KB LDS-resident W slice.

__global__ __launch_bounds__(256) void lstm_step_kernel(
    const __hip_bfloat16* __restrict__ XG,    // [16384][4096]
    const __hip_bfloat16* __restrict__ WhT,   // [4096][1024]
    const __hip_bfloat16* __restrict__ Hprev, // [64][1024]
    __hip_bfloat16* __restrict__ Hnext,       // [64][1024]
    float* __restrict__ Cst,                  // [64][1024]
    int t, float* __restrict__ outH, float* __restrict__ outC) {
  __shared__ char lds[65536 + 64 * 33 * 4];
  char* Wlds = lds;
  float* gates = (float*)(lds + 65536);
  const int tid = threadIdx.x;
  const int lane = tid & 63, wave = tid >> 6;
  const int jb = blockIdx.x;  // 0..127

  // stage W slice: 32 LDS rows (q*8+rr) x 2048B, swizzled source
#pragma unroll
  for (int c = 0; c < 16; ++c) {
    int u = c * 256 + tid;
    int row = u >> 7, cu = u & 127;
    size_t n = (size_t)(row >> 3) * 1024 + (size_t)jb * 8 + (row & 7);
    const char* src = (const char*)(WhT + n * 1024) + ((cu * 16) ^ ((row & 7) << 4));
    gload_lds16(src, Wlds + c * 4096 + wave * 1024);
  }
  __syncthreads();

  const int lr = lane & 15;
  const int lk = (lane >> 4) << 4;
  const int ls = (lane & 7) << 4;

  f32x4 acc[2] = {};
  const char* Hrow = (const char*)Hprev + (size_t)(wave * 16 + lr) * 2048;
#pragma unroll
  for (int k = 0; k < 32; ++k) {
    bf16x8 a = *(const bf16x8*)(Hrow + k * 64 + lk);
#pragma unroll
    for (int n = 0; n < 2; ++n) {
      int wr = n * 16 + lr;
      bf16x8 b = *(const bf16x8*)(Wlds + wr * 2048 + ((k * 64 + lk) ^ ls));
      acc[n] = __builtin_amdgcn_mfma_f32_16x16x32_bf16(a, b, acc[n], 0, 0, 0);
    }
  }

  // gate pre-activations (sans XG) to LDS; col = gate*8 + j, padded stride 33
#pragma unroll
  for (int n = 0; n < 2; ++n)
#pragma unroll
    for (int r = 0; r < 4; ++r) {
      int b = wave * 16 + ((lane >> 4) << 2) + r;
      gates[b * 33 + n * 16 + lr] = acc[n][r];
    }
  __syncthreads();

  // cell update: 512 (b,j) pairs per WG
#pragma unroll
  for (int i = 0; i < 2; ++i) {
    int e = i * 256 + tid;
    int b = e >> 3, j = e & 7;
    int jg = jb * 8 + j;
    const __hip_bfloat16* xg = XG + ((size_t)t * 64 + b) * 4096 + jg;
    float gi = gates[b * 33 + 0  + j] + __bfloat162float(xg[0]);
    float gf = gates[b * 33 + 8  + j] + __bfloat162float(xg[1024]);
    float go = gates[b * 33 + 16 + j] + __bfloat162float(xg[2048]);
    float gc = gates[b * 33 + 24 + j] + __bfloat162float(xg[3072]);
    float I = sigm(gi), F = sigm(gf), O = sigm(go);
    float Ct = tanh_fast(gc);
    size_t ci = (size_t)b * 1024 + jg;
    float Cn = F * Cst[ci] + I * Ct;
    Cst[ci] = Cn;
    float Hn = O * tanh_fast(Cn);
    Hnext[ci] = __float2bfloat16(Hn);
    if (outH) { outH[ci] = Hn; outC[ci] = Cn; }
  }
}

// ---------------- host ----------------

extern "C" void kernel_launch(void* const* d_in, const int* in_sizes, int n_in,
                              void* d_out, int out_size, void* d_ws, size_t ws_size,
                              hipStream_t stream) {
  const float* X   = (const float*)d_in[0];
  const float* H0  = (const float*)d_in[1];
  const float* C0  = (const float*)d_in[2];
  const float* Wxi = (const float*)d_in[3];
  const float* Whi = (const float*)d_in[4];
  const float* bi  = (const float*)d_in[5];
  const float* Wxf = (const float*)d_in[6];
  const float* Whf = (const float*)d_in[7];
  const float* bf  = (const float*)d_in[8];
  const float* Wxo = (const float*)d_in[9];
  const float* Who = (const float*)d_in[10];
  const float* bo  = (const float*)d_in[11];
  const float* Wxc = (const float*)d_in[12];
  const float* Whc = (const float*)d_in[13];
  const float* bc  = (const float*)d_in[14];
  const float* Whq = (const float*)d_in[15];
  const float* bq  = (const float*)d_in[16];

  char* ws = (char*)d_ws;
  size_t off = 0;
  auto alloc = [&](size_t bytes) {
    char* p = ws + off;
    off += (bytes + 255) & ~(size_t)255;
    return p;
  };
  __hip_bfloat16* Xbf  = (__hip_bfloat16*)alloc(16384ull * 1024 * 2);  // 32 MB
  __hip_bfloat16* WxT  = (__hip_bfloat16*)alloc(4096ull * 1024 * 2);   // 8 MB
  __hip_bfloat16* WhT  = (__hip_bfloat16*)alloc(4096ull * 1024 * 2);   // 8 MB
  __hip_bfloat16* WhqT = (__hip_bfloat16*)alloc(1024ull * 1024 * 2);   // 2 MB
  float*          b4   = (float*)alloc(4096 * 4);
  float*          Cws  = (float*)alloc(65536 * 4);
  __hip_bfloat16* Hbuf = (__hip_bfloat16*)alloc(257ull * 65536 * 2);   // 32.1 MB
  __hip_bfloat16* XG   = (__hip_bfloat16*)alloc(16384ull * 4096 * 2);  // 128 MB
  (void)ws_size; (void)in_sizes; (void)n_in; (void)out_size;

  convert_x_kernel<<<8192, 256, 0, stream>>>(X, Xbf);
  init_kernel<<<272, 256, 0, stream>>>(H0, C0, bi, bf, bo, bc, Hbuf, Cws, b4);
  PackArgs pa;
  pa.s[0] = Wxi; pa.s[1] = Wxf; pa.s[2] = Wxo; pa.s[3] = Wxc;
  pa.s[4] = Whi; pa.s[5] = Whf; pa.s[6] = Who; pa.s[7] = Whc;
  pa.s[8] = Whq;
  pack_weights_kernel<<<dim3(32, 32, 9), dim3(32, 8), 0, stream>>>(pa, WxT, WhT, WhqT);

  gemm_bt_kernel<true><<<dim3(128, 32), 256, 0, stream>>>(Xbf, WxT, b4, XG, 4096);

  float* outY = (float*)d_out;
  float* outH = outY + 16777216;
  float* outC = outH + 65536;
  for (int t = 0; t < 256; ++t) {
    lstm_step_kernel<<<128, 256, 0, stream>>>(
        XG, WhT, Hbuf + (size_t)t * 65536, Hbuf + (size_t)(t + 1) * 65536, Cws, t,
        (t == 255) ? outH : nullptr, (t == 255) ? outC : nullptr);
  }

  gemm_bt_kernel<false><<<dim3(128, 8), 256, 0, stream>>>(Hbuf + 65536, WhqT, bq, d_out, 1024);
}